// Round 19
// baseline (272.332 us; speedup 1.0000x reference)
//
#include <hip/hip_runtime.h>
#include <hip/hip_bf16.h>

// FlowEmbedding (B=4, N=M=4096, C=64, S=32, mlp=[64,64,64]) — f32 I/O.
// R19: R15's 512-thread dual-wave-group design (2x waves/CU, constant atomic
//      count) WITHOUT the min-waves launch bound that caused VGPR=64 spills.
//      Plus R17's parallel reduceG and R14's mraw/epi structure.

#define N_ 4096
#define S_ 32
#define PTOT 524288.0f   // B*N*S

typedef unsigned short u16;
typedef unsigned int   u32;
typedef unsigned long long u64;
typedef __attribute__((ext_vector_type(8))) short short8;  // 8 bf16 (4 VGPR)
typedef __attribute__((ext_vector_type(4))) float f32x4;

__device__ __forceinline__ float b2f(u16 u){
  union { u32 i; float f; } x; x.i = ((u32)u) << 16; return x.f;
}
__device__ __forceinline__ u16 f2b(float f){
  __hip_bfloat16 h = __float2bfloat16(f);
  return *(u16*)&h;
}
// monotone float<->uint mapping for signed atomicMax
__device__ __forceinline__ u32 fenc(float f){
  u32 u = __float_as_uint(f);
  return (u & 0x80000000u) ? ~u : (u | 0x80000000u);
}
__device__ __forceinline__ float fdec(u32 k){
  return __uint_as_float((k & 0x80000000u) ? (k & 0x7FFFFFFFu) : ~k);
}
// swizzled u16 index into a [64][64] bf16 LDS tile (rows 128 B): conflict-free
__device__ __forceinline__ int TIX(int r, int c){ return (r << 6) + (c ^ ((r & 7) << 3)); }
#define MFMA16(a,b,c) __builtin_amdgcn_mfma_f32_16x16x32_bf16((a),(b),(c),0,0,0)

// ---------------- copy pos1 (output 0 passthrough) ---------------------------
__global__ void k_copy(const uint4* __restrict__ s, uint4* __restrict__ d){
  int i = blockIdx.x * 256 + threadIdx.x;   // 48 x 256 = 12288 exact
  d[i] = s[i];
}

// ---------------- KNN: per-lane counting + parallel rank-select --------------
#define PLCNT(T, OUT) { int _c = 0;                                           \
  _Pragma("unroll")                                                           \
  for (int _it = 0; _it < 64; ++_it) _c += (dl[_it] < (T)) ? 1 : 0;           \
  _Pragma("unroll")                                                           \
  for (int _d = 1; _d < 64; _d <<= 1) _c += __shfl_xor(_c, _d);               \
  OUT = (u32)_c; }

__global__ __launch_bounds__(256) void k_knn(const float* __restrict__ pos1,
        const float* __restrict__ pos2, int* __restrict__ idxb){
  __shared__ u64 lkey[4][96];
  int b = blockIdx.y;
  int l = threadIdx.x & 63;
  int w = threadIdx.x >> 6;
  int n = blockIdx.x * 4 + w;
  const float* p1 = pos1 + b * 3 * N_;
  const float* p2 = pos2 + b * 3 * N_;
  float qx = p1[n], qy = p1[N_ + n], qz = p1[2 * N_ + n];
  float dl[64];
  float minv = 3.4e38f;
  #pragma unroll
  for (int it = 0; it < 16; ++it){          // float4 loads: 4 points/iter
    int j0 = it * 256 + l * 4;
    float4 xv = *(const float4*)(p2 + j0);
    float4 yv = *(const float4*)(p2 + N_ + j0);
    float4 zv = *(const float4*)(p2 + 2 * N_ + j0);
    float dx, dy, dz, d;
    dx=xv.x-qx; dy=yv.x-qy; dz=zv.x-qz; d=fmaf(dx,dx,fmaf(dy,dy,dz*dz)); dl[it*4+0]=d; minv=fminf(minv,d);
    dx=xv.y-qx; dy=yv.y-qy; dz=zv.y-qz; d=fmaf(dx,dx,fmaf(dy,dy,dz*dz)); dl[it*4+1]=d; minv=fminf(minv,d);
    dx=xv.z-qx; dy=yv.z-qy; dz=zv.z-qz; d=fmaf(dx,dx,fmaf(dy,dy,dz*dz)); dl[it*4+2]=d; minv=fminf(minv,d);
    dx=xv.w-qx; dy=yv.w-qy; dz=zv.w-qz; d=fmaf(dx,dx,fmaf(dy,dy,dz*dz)); dl[it*4+3]=d; minv=fminf(minv,d);
  }
  #pragma unroll
  for (int d2 = 1; d2 < 64; d2 <<= 1) minv = fminf(minv, __shfl_xor(minv, d2));
  u32 lo = __float_as_uint(minv);
  u32 hi = lo + (5u << 23); if (hi > 0x7F800000u) hi = 0x7F800000u;
  u32 step = 2u << 23;
  u32 K = 0;
  for (int e = 0; e < 12; ++e){
    PLCNT(__uint_as_float(hi), K)
    if (K >= 32u) break;
    lo = hi;
    hi += step; if (hi > 0x7F800000u) hi = 0x7F800000u;
    step <<= 1;
  }
  if (K < 32u){ hi = 0x7F800000u; PLCNT(__uint_as_float(hi), K) }
  for (int itr = 0; itr < 28 && K > 96u && (hi - lo) > 1u; ++itr){
    u32 mid = (lo + hi) >> 1, c;
    PLCNT(__uint_as_float(mid), c)
    if (c >= 32u){ hi = mid; K = c; } else lo = mid;
  }
  float T = __uint_as_float(hi);
  lkey[w][l] = ~0ull;
  if (l < 32) lkey[w][64 + l] = ~0ull;
  int myc = 0;
  #pragma unroll
  for (int it = 0; it < 64; ++it) myc += (dl[it] < T) ? 1 : 0;
  int pre = myc;
  #pragma unroll
  for (int d2 = 1; d2 < 64; d2 <<= 1){
    int t2 = __shfl_up(pre, d2); if (l >= d2) pre += t2;
  }
  int slot = pre - myc;
  for (int it = 0; it < 64; ++it){
    if (dl[it] < T){
      if (slot < 96)
        lkey[w][slot] = ((u64)__float_as_uint(dl[it]) << 32)
                      | (u32)((it >> 2) * 256 + l * 4 + (it & 3));
      slot++;
    }
  }
  int Kc = (int)(K > 96u ? 96u : K);
  u64 k0 = lkey[w][l];
  u64 k1 = (l < 32) ? lkey[w][64 + l] : ~0ull;
  int r0 = 0, r1 = 0;
  for (int j = 0; j < 96; j += 2){
    ulonglong2 kp = *(const ulonglong2*)&lkey[w][j];
    r0 += (kp.x < k0) + (kp.y < k0);
    r1 += (kp.x < k1) + (kp.y < k1);
  }
  unsigned long long m0 = __ballot((l < Kc) && (r0 == 0));
  u32 nearest;
  if (m0) nearest = (u32)__shfl((int)(u32)k0, __builtin_ctzll(m0));
  else {
    unsigned long long m1 = __ballot((l + 64 < Kc) && (r1 == 0));
    nearest = (u32)__shfl((int)(u32)k1, __builtin_ctzll(m1));
  }
  int* op = idxb + (b * N_ + n) * S_;
  float d0 = __uint_as_float((u32)(k0 >> 32));
  float d1 = __uint_as_float((u32)(k1 >> 32));
  if ((l < Kc) && (r0 < 32))      op[r0] = (d0 > 25.0f) ? (int)nearest : (int)(u32)k0;
  if ((l + 64 < Kc) && (r1 < 32)) op[r1] = (d1 > 25.0f) ? (int)nearest : (int)(u32)k1;
}

// ---------------- layer-0 factorization -> bf16: A (MODE=0) / Cn (MODE=1) ---
template<int MODE>
__global__ __launch_bounds__(256) void k_precomp(const float* __restrict__ posx,
        const float* __restrict__ featx, const float* __restrict__ W0,
        u16* __restrict__ outp){
  __shared__ float Ws[67][65];
  __shared__ float Xs[67][65];
  int b = blockIdx.y, j0 = blockIdx.x * 64, t = threadIdx.x;
  for (int e = t; e < 67 * 64; e += 256){
    int r = e >> 6, o = e & 63;
    int wc = (MODE == 0) ? r : (r < 3 ? r : r + 64);
    Ws[r][o] = W0[o * 131 + wc];
    float x;
    if (r < 3){ x = posx[(b * 3 + r) * N_ + j0 + o]; if (MODE) x = -x; }
    else        x = featx[(b * 64 + (r - 3)) * N_ + j0 + o];
    Xs[r][o] = x;
  }
  __syncthreads();
  int og = t & 15, sl = t >> 4;
  float acc[4][4] = {};
  for (int r = 0; r < 67; ++r){
    float w0v = Ws[r][og*4+0], w1v = Ws[r][og*4+1], w2v = Ws[r][og*4+2], w3v = Ws[r][og*4+3];
    #pragma unroll
    for (int c = 0; c < 4; ++c){
      float xv = Xs[r][sl*4+c];
      acc[c][0] += xv*w0v; acc[c][1] += xv*w1v; acc[c][2] += xv*w2v; acc[c][3] += xv*w3v;
    }
  }
  #pragma unroll
  for (int c = 0; c < 4; ++c){
    ushort4 val;
    val.x = f2b(acc[c][0]); val.y = f2b(acc[c][1]);
    val.z = f2b(acc[c][2]); val.w = f2b(acc[c][3]);
    *(ushort4*)&outp[(((size_t)(b * N_ + j0 + sl*4 + c)) << 6) + og*4] = val;
  }
}

// ---------------- convert W2 f32 -> raw bf16 [o][c] --------------------------
__global__ void k_cvtW2(const float* __restrict__ W, u16* __restrict__ Wb){
  int t = threadIdx.x;
  for (int e = t; e < 4096; e += 256) Wb[e] = f2b(W[e]);
}

// ---------------- stats of h0: bf16 gather, 512 thr (two query halves) ------
__global__ __launch_bounds__(512) void k_stats0(const int* __restrict__ idxb,
    const u16* __restrict__ A, const u16* __restrict__ Cn,
    float* __restrict__ sp1, float* __restrict__ sp2){
  int b = blockIdx.y, n0 = blockIdx.x * 32;
  int t = threadIdx.x;
  int c4 = t & 15, sq = (t >> 4) & 15, g = t >> 8;
  float4 a1 = {0,0,0,0}, a2 = {0,0,0,0};
  for (int q = g * 16; q < g * 16 + 16; ++q){
    int n = n0 + q;
    ushort4 cu = *(const ushort4*)&Cn[(((size_t)(b * N_ + n)) << 6) + c4 * 4];
    float cx = b2f(cu.x), cy = b2f(cu.y), cz = b2f(cu.z), cw = b2f(cu.w);
    const int* ip = idxb + (b * N_ + n) * 32;
    #pragma unroll
    for (int ss = 0; ss < 2; ++ss){
      int j = ip[sq + ss * 16];
      ushort4 au = *(const ushort4*)&A[(((size_t)(b * N_ + j)) << 6) + c4 * 4];
      float h0 = b2f(au.x) + cx, h1 = b2f(au.y) + cy;
      float h2 = b2f(au.z) + cz, h3 = b2f(au.w) + cw;
      a1.x += h0; a1.y += h1; a1.z += h2; a1.w += h3;
      a2.x += h0*h0; a2.y += h1*h1; a2.z += h2*h2; a2.w += h3*h3;
    }
  }
  __shared__ float red1[32][64];
  __shared__ float red2[32][64];
  *(float4*)&red1[g*16 + sq][c4*4] = a1;
  *(float4*)&red2[g*16 + sq][c4*4] = a2;
  __syncthreads();
  int slot = (blockIdx.x + (blockIdx.y << 7)) & 63;
  if (t < 64){
    float s1 = 0.f, s2 = 0.f;
    #pragma unroll
    for (int k = 0; k < 32; ++k){ s1 += red1[k][t]; s2 += red2[k][t]; }
    atomicAdd(&sp1[slot * 64 + t], s1);
    atomicAdd(&sp2[slot * 64 + t], s2);
  }
}

// ---------------- BN param kernels (parallelized) ----------------------------
__global__ __launch_bounds__(256) void k_bn0(const float* __restrict__ sp1,
    const float* __restrict__ sp2, const float* g, const float* bb, float* bnp){
  __shared__ float red1[4][64];
  __shared__ float red2[4][64];
  int t = threadIdx.x, c = t & 63, s = t >> 6;
  float s1 = 0.f, s2 = 0.f;
  for (int k = s * 16; k < s * 16 + 16; ++k){
    s1 += sp1[k * 64 + c]; s2 += sp2[k * 64 + c];
  }
  red1[s][c] = s1; red2[s][c] = s2;
  __syncthreads();
  if (t < 64){
    float a1 = red1[0][c] + red1[1][c] + red1[2][c] + red1[3][c];
    float a2 = red2[0][c] + red2[1][c] + red2[2][c] + red2[3][c];
    float m = a1 * (1.0f / PTOT);
    float v = a2 * (1.0f / PTOT) - m * m;
    v = v > 0.f ? v : 0.f;
    float sc = g[c] * rsqrtf(v + 1e-5f);
    bnp[c] = sc; bnp[64 + c] = bb[c] - m * sc;
  }
}

__global__ __launch_bounds__(256) void k_bnW(const float* __restrict__ W,
    const float* __restrict__ rp, const float* __restrict__ G, const float* g,
    const float* bb, float* bnp, u16* __restrict__ Wb){
  __shared__ float Ws[64][65];
  __shared__ float Gs[64][65];
  __shared__ float r_s[64];
  __shared__ float redA[4][64];
  __shared__ float redB[4][64];
  __shared__ float scs[64];
  int t = threadIdx.x, o = t & 63, s = t >> 6;
  for (int e = t; e < 4096; e += 256){
    Ws[e >> 6][e & 63] = W[e];
    Gs[e >> 6][e & 63] = G[e];
  }
  float rv = 0.f;
  for (int k = s * 32; k < s * 32 + 32; ++k) rv += rp[k * 64 + o];
  redA[s][o] = rv;
  __syncthreads();
  if (s == 0) r_s[o] = redA[0][o] + redA[1][o] + redA[2][o] + redA[3][o];
  __syncthreads();
  float pm = 0.f, pq = 0.f;
  for (int c = s * 16; c < s * 16 + 16; ++c){
    float t1 = 0.f;
    #pragma unroll
    for (int d = 0; d < 64; ++d) t1 = fmaf(Gs[c][d], Ws[o][d], t1);
    pm = fmaf(Ws[o][c], r_s[c], pm);
    pq = fmaf(Ws[o][c], t1, pq);
  }
  __syncthreads();
  redA[s][o] = pm; redB[s][o] = pq;
  __syncthreads();
  if (t < 64){
    float mean = redA[0][o] + redA[1][o] + redA[2][o] + redA[3][o];
    float qq   = redB[0][o] + redB[1][o] + redB[2][o] + redB[3][o];
    float m = mean * (1.0f / PTOT);
    float v = qq * (1.0f / PTOT) - m * m;
    v = v > 0.f ? v : 0.f;
    float sc = g[o] * rsqrtf(v + 1e-5f);
    bnp[o] = sc; bnp[64 + o] = bb[o] - m * sc;
    scs[o] = sc;
  }
  __syncthreads();
  for (int e = t; e < 4096; e += 256){
    int oo = e >> 6, cc = e & 63;
    Wb[e] = f2b(scs[oo] * Ws[oo][cc]);
  }
}

// ------ reduce 128 partial grams -> G (parallel slot-split, 16x8 grid) ------
__global__ void k_reduceG(float* __restrict__ Gp, float* __restrict__ Gout){
  int e = blockIdx.x * 256 + threadIdx.x;
  int s0 = blockIdx.y * 16;
  float v = 0.f;
  for (int s = s0; s < s0 + 16; ++s) v += Gp[s * 4096 + e];
  atomicAdd(&Gout[e], v);                    // Gout pre-zeroed by memset
  for (int s = s0; s < s0 + 16; ++s) Gp[s * 4096 + e] = 0.f;
}

// gather one 64-point chunk from bf16 A/Cn: y0 = relu(fma(sc0, A+Cn, sh0))
#define GATHER_Y0(YARR)                                                       \
  int nq = n0 + ch * 2 + (l >> 5);                                            \
  int jj = idxb[((b << 12) + nq) * 32 + (l & 31)];                            \
  const u16* ap = A + (((size_t)((b << 12) + jj)) << 6) + (wl << 4);          \
  const u16* cp = Cn + (((size_t)((b << 12) + nq)) << 6) + (wl << 4);         \
  short8 ga0 = *(const short8*)(ap);                                          \
  short8 ga1 = *(const short8*)(ap + 8);                                      \
  short8 gc0 = *(const short8*)(cp);                                          \
  short8 gc1 = *(const short8*)(cp + 8);                                      \
  float YARR[16];                                                             \
  _Pragma("unroll")                                                           \
  for (int kk = 0; kk < 16; ++kk){                                            \
    u16 ae = (kk < 8) ? (u16)ga0[kk] : (u16)ga1[kk - 8];                      \
    u16 ce = (kk < 8) ? (u16)gc0[kk] : (u16)gc1[kk - 8];                      \
    float hv = b2f(ae) + b2f(ce);                                             \
    float sc = ((const float*)scv)[kk], sh = ((const float*)shv)[kk];         \
    YARR[kk] = fmaxf(fmaf(sc, hv, sh), 0.f);                                  \
  }

#define LOAD_BN0                                                              \
  float4 scv[4], shv[4];                                                      \
  _Pragma("unroll")                                                           \
  for (int k = 0; k < 4; ++k){                                                \
    scv[k] = *((const float4*)bnp0 + (wl << 2) + k);                          \
    shv[k] = *((const float4*)bnp0 + 16 + (wl << 2) + k);                     \
  }

// ---------------- gram0: 512 thr, dual-chunk; FAT exports y0 images ---------
template<int FAT>
__global__ __launch_bounds__(512) void k_gram0(const int* __restrict__ idxb,
    const u16* __restrict__ A, const u16* __restrict__ Cn,
    const float* __restrict__ bnp0, float* __restrict__ Gp, float* __restrict__ rp0,
    u16* __restrict__ y0img){
  __shared__ u16 yc[8192];                   // y0 [c][p] x2 groups
  __shared__ u16 yp[FAT ? 8192 : 128];       // y0 [p][c] x2, export only
  int b = blockIdx.y, n0 = blockIdx.x * 32, t = threadIdx.x;
  int l = t & 63, w = t >> 6;
  int g = w >> 2, wl = w & 3;
  int tg = (wl << 6) | l;
  int go = g << 12;
  LOAD_BN0
  f32x4 acc[4] = {};
  float rsum[16] = {};
  for (int chb = 0; chb < 16; chb += 2){
    int ch = chb + g;
    GATHER_Y0(yv)
    #pragma unroll
    for (int k = 0; k < 16; ++k){
      rsum[k] += yv[k];
      yc[go + TIX((wl << 4) + k, l)] = f2b(yv[k]);
    }
    if (FAT){
      short8 s0v, s1v;
      #pragma unroll
      for (int i = 0; i < 8; ++i){ s0v[i] = (short)f2b(yv[i]); s1v[i] = (short)f2b(yv[8+i]); }
      *(short8*)&yp[go + TIX(l, (wl<<4))] = s0v;
      *(short8*)&yp[go + TIX(l, (wl<<4) + 8)] = s1v;
    }
    __syncthreads();
    #pragma unroll
    for (int ks = 0; ks < 2; ++ks){
      short8 bf = *(const short8*)&yc[go + TIX((wl << 4) + (l & 15), ks * 32 + ((l >> 4) << 3))];
      #pragma unroll
      for (int ta = 0; ta < 4; ++ta){
        short8 af = *(const short8*)&yc[go + TIX(ta * 16 + (l & 15), ks * 32 + ((l >> 4) << 3))];
        acc[ta] = MFMA16(af, bf, acc[ta]);
      }
    }
    if (FAT){                                // export group tile, coalesced
      int rr = tg >> 2, c0i = (tg & 3) << 4;
      short8 e0 = *(const short8*)&yp[go + TIX(rr, c0i)];
      short8 e1 = *(const short8*)&yp[go + TIX(rr, c0i + 8)];
      size_t gb = ((((size_t)(((blockIdx.y << 7) | blockIdx.x) << 4) + ch) << 12)
                   + (rr << 6) + c0i);
      *(short8*)&y0img[gb] = e0;
      *(short8*)&y0img[gb + 8] = e1;
    }
    __syncthreads();
  }
  int slot = ((blockIdx.x << 2) + blockIdx.y) & 127;
  float* gp = Gp + slot * 4096;
  #pragma unroll
  for (int i = 0; i < 16; ++i){
    float v = rsum[i];
    #pragma unroll
    for (int s = 32; s >= 1; s >>= 1) v += __shfl_xor(v, s);
    if (l == 0) atomicAdd(&rp0[slot * 64 + (wl<<4) + i], v);
  }
  // pair-reduce acc across groups via LDS, single atomic dump by group 0
  float* redG = (float*)yc;                  // 16 KB scratch
  if (g == 1){
    #pragma unroll
    for (int ta = 0; ta < 4; ++ta)
      #pragma unroll
      for (int r = 0; r < 4; ++r)
        redG[(ta*16 + ((l>>4)<<2) + r) * 64 + (wl<<4) + (l & 15)] = acc[ta][r];
  }
  __syncthreads();
  if (g == 0){
    #pragma unroll
    for (int ta = 0; ta < 4; ++ta)
      #pragma unroll
      for (int r = 0; r < 4; ++r){
        int ix = (ta*16 + ((l>>4)<<2) + r) * 64 + (wl<<4) + (l & 15);
        atomicAdd(&gp[ix], acc[ta][r] + redG[ix]);
      }
  }
}

// ---- gram1: 512 thr, dual-chunk; y1=relu(W1b*y0+sh1); G1; h2 maxpool -------
template<int FAT>
__global__ __launch_bounds__(512) void k_gram1(const int* __restrict__ idxb,
    const u16* __restrict__ A, const u16* __restrict__ Cn,
    const float* __restrict__ bnp0, const u16* __restrict__ W1b,
    const u16* __restrict__ W2r, const float* __restrict__ bnp1,
    float* __restrict__ Gp, float* __restrict__ rp1,
    const u16* __restrict__ y0img, float* __restrict__ mraw){
  __shared__ u16 yp[8192];                   // y0 [p][c] x2
  __shared__ u16 y1c[8192];                  // y1 [c][p] x2
  __shared__ u16 y1p[8192];                  // y1 [p][c] x2
  __shared__ u32 omax[2048];                 // [qloc 0..31][o] fenc-coded
  __shared__ float sh1[64];
  __shared__ float rsh[64];
  int b = blockIdx.y, n0 = blockIdx.x * 32, t = threadIdx.x;
  int l = t & 63, w = t >> 6;
  int g = w >> 2, wl = w & 3;
  int tg = (wl << 6) | l;
  int go = g << 12;
  LOAD_BN0
  if (t < 64){ sh1[t] = bnp1[64 + t]; rsh[t] = 0.f; }
  for (int e = t; e < 2048; e += 512) omax[e] = 0u;
  short8 wf[4][2], wf2[4][2];
  #pragma unroll
  for (int to = 0; to < 4; ++to)
    #pragma unroll
    for (int ks = 0; ks < 2; ++ks){
      wf[to][ks]  = *(const short8*)&W1b[(to*16 + (l & 15)) * 64 + ks*32 + ((l>>4)<<3)];
      wf2[to][ks] = *(const short8*)&W2r[(to*16 + (l & 15)) * 64 + ks*32 + ((l>>4)<<3)];
    }
  __syncthreads();
  float sh1v[4][4];
  #pragma unroll
  for (int to = 0; to < 4; ++to)
    #pragma unroll
    for (int r = 0; r < 4; ++r)
      sh1v[to][r] = sh1[to*16 + ((l>>4)<<2) + r];
  f32x4 gacc[4] = {};
  float rs[4][4] = {};
  for (int chb = 0; chb < 16; chb += 2){
    int ch = chb + g;
    if (FAT){
      int rr = tg >> 2, c0i = (tg & 3) << 4;
      size_t gb = ((((size_t)(((blockIdx.y << 7) | blockIdx.x) << 4) + ch) << 12)
                   + (rr << 6) + c0i);
      short8 e0 = *(const short8*)&y0img[gb];
      short8 e1 = *(const short8*)&y0img[gb + 8];
      *(short8*)&yp[go + TIX(rr, c0i)] = e0;
      *(short8*)&yp[go + TIX(rr, c0i + 8)] = e1;
    } else {
      GATHER_Y0(yv)
      short8 s0, s1;
      #pragma unroll
      for (int i = 0; i < 8; ++i){ s0[i] = (short)f2b(yv[i]); s1[i] = (short)f2b(yv[8+i]); }
      *(short8*)&yp[go + TIX(l, (wl<<4))] = s0;
      *(short8*)&yp[go + TIX(l, (wl<<4) + 8)] = s1;
    }
    __syncthreads();
    // layer1: D[o][p] = sum_c W1b[o][c] * y0[c][p]
    short8 bf0 = *(const short8*)&yp[go + TIX((wl<<4) + (l & 15), ((l>>4)<<3))];
    short8 bf1 = *(const short8*)&yp[go + TIX((wl<<4) + (l & 15), 32 + ((l>>4)<<3))];
    f32x4 h[4] = {};
    #pragma unroll
    for (int to = 0; to < 4; ++to){
      h[to] = MFMA16(wf[to][0], bf0, h[to]);
      h[to] = MFMA16(wf[to][1], bf1, h[to]);
    }
    int pcol = (wl<<4) + (l & 15);
    #pragma unroll
    for (int to = 0; to < 4; ++to){
      ushort4 sv;
      #pragma unroll
      for (int r = 0; r < 4; ++r){
        int o = to*16 + ((l>>4)<<2) + r;
        float y = h[to][r] + sh1v[to][r];
        y = y > 0.f ? y : 0.f;
        rs[to][r] += y;
        u16 yb = f2b(y);
        y1c[go + TIX(o, pcol)] = yb;
        ((u16*)&sv)[r] = yb;
      }
      *(ushort4*)&y1p[go + TIX(pcol, to*16 + ((l>>4)<<2))] = sv;
    }
    __syncthreads();
    // gram over y1
    #pragma unroll
    for (int ks = 0; ks < 2; ++ks){
      short8 bf = *(const short8*)&y1c[go + TIX((wl<<4) + (l & 15), ks*32 + ((l>>4)<<3))];
      #pragma unroll
      for (int ta = 0; ta < 4; ++ta){
        short8 af = *(const short8*)&y1c[go + TIX(ta*16 + (l & 15), ks*32 + ((l>>4)<<3))];
        gacc[ta] = MFMA16(af, bf, gacc[ta]);
      }
    }
    // layer2 raw + maxpool (bn2 applied in k_epi; s2>0 since g2=1)
    short8 c0 = *(const short8*)&y1p[go + TIX(pcol, ((l>>4)<<3))];
    short8 c1 = *(const short8*)&y1p[go + TIX(pcol, 32 + ((l>>4)<<3))];
    f32x4 h2[4] = {};
    #pragma unroll
    for (int to = 0; to < 4; ++to){
      h2[to] = MFMA16(wf2[to][0], c0, h2[to]);
      h2[to] = MFMA16(wf2[to][1], c1, h2[to]);
    }
    int qloc = ch * 2 + (wl >> 1);
    #pragma unroll
    for (int to = 0; to < 4; ++to)
      #pragma unroll
      for (int r = 0; r < 4; ++r){
        float m = h2[to][r];
        #pragma unroll
        for (int s = 1; s <= 8; s <<= 1) m = fmaxf(m, __shfl_xor(m, s));
        if ((l & 15) == 0)
          atomicMax(&omax[qloc*64 + to*16 + ((l>>4)<<2) + r], fenc(m));
      }
    __syncthreads();
  }
  int slot = ((blockIdx.x << 2) + blockIdx.y) & 127;
  float* gp = Gp + slot * 4096;
  // rs reduce (all 8 waves -> LDS rsh)
  #pragma unroll
  for (int to = 0; to < 4; ++to)
    #pragma unroll
    for (int r = 0; r < 4; ++r){
      float v = rs[to][r];
      #pragma unroll
      for (int s = 1; s <= 8; s <<= 1) v += __shfl_xor(v, s);
      if ((l & 15) == 0) atomicAdd(&rsh[to*16 + ((l>>4)<<2) + r], v);
    }
  // pair-reduce gacc via LDS (reuse yp), single atomic dump by group 0
  float* redG = (float*)yp;
  if (g == 1){
    #pragma unroll
    for (int ta = 0; ta < 4; ++ta)
      #pragma unroll
      for (int r = 0; r < 4; ++r)
        redG[(ta*16 + ((l>>4)<<2) + r) * 64 + (wl<<4) + (l & 15)] = gacc[ta][r];
  }
  __syncthreads();
  if (g == 0){
    #pragma unroll
    for (int ta = 0; ta < 4; ++ta)
      #pragma unroll
      for (int r = 0; r < 4; ++r){
        int ix = (ta*16 + ((l>>4)<<2) + r) * 64 + (wl<<4) + (l & 15);
        atomicAdd(&gp[ix], gacc[ta][r] + redG[ix]);
      }
  }
  if (t < 64) atomicAdd(&rp1[slot * 64 + t], rsh[t]);
  // write raw maxima: block owns queries n0..n0+31 exclusively -> plain stores
  for (int e = t; e < 2048; e += 512){
    int q = e >> 6, o = e & 63;
    mraw[(((size_t)((b << 12) + n0 + q)) << 6) + o] = fdec(omax[e]);
  }
}

// ---------------- epilogue: out = relu(s2*mraw + t2), transpose -------------
__global__ __launch_bounds__(256) void k_epi(const float* __restrict__ mraw,
    const float* __restrict__ bnp2, float* __restrict__ outp){
  __shared__ float tile[64][65];
  int b = blockIdx.y, n0 = blockIdx.x * 64, t = threadIdx.x;
  int o = t & 63, w = t >> 6;
  float sc = bnp2[o], sh = bnp2[64 + o];
  #pragma unroll
  for (int i = 0; i < 16; ++i){
    int n = i * 4 + w;
    float m = mraw[(((size_t)((b << 12) + n0 + n)) << 6) + o];
    float y = fmaf(sc, m, sh);
    tile[n][o] = y > 0.f ? y : 0.f;
  }
  __syncthreads();
  #pragma unroll
  for (int i = 0; i < 16; ++i){
    int oo = i * 4 + w;
    outp[49152 + ((size_t)((b << 6) + oo)) * N_ + n0 + o] = tile[o][oo];
  }
}

extern "C" void kernel_launch(void* const* d_in, const int* in_sizes, int n_in,
                              void* d_out, int out_size, void* d_ws, size_t ws_size,
                              hipStream_t stream){
  (void)in_sizes; (void)n_in; (void)out_size;
  const float* pos1 = (const float*)d_in[0];
  const float* pos2 = (const float*)d_in[1];
  const float* f1   = (const float*)d_in[2];
  const float* f2   = (const float*)d_in[3];
  const float* W0   = (const float*)d_in[4];
  const float* g0   = (const float*)d_in[5];
  const float* b0   = (const float*)d_in[6];
  const float* W1   = (const float*)d_in[7];
  const float* g1   = (const float*)d_in[8];
  const float* b1   = (const float*)d_in[9];
  const float* W2   = (const float*)d_in[10];
  const float* g2   = (const float*)d_in[11];
  const float* b2   = (const float*)d_in[12];

  char* ws = (char*)d_ws;
  int*   idxb = (int*)ws;                        // 2 MiB: idx[B][N][32]
  u16*   A    = (u16*)(ws + (2u << 20));         // 2 MiB: A[b][j][64] bf16
  u16*   Cn   = (u16*)(ws + (4u << 20));         // 2 MiB: Cn[b][n][64] bf16
  float* Gp   = (float*)(ws + (6u << 20));       // 2 MiB: 128 x 4096 partials
  float* st2  = (float*)(ws + (8u << 20));
  float* rp0  = st2;               // 128*64 = 8192
  float* rp1  = st2 + 8192;        // 8192
  float* sp1  = st2 + 16384;       // 64*64 = 4096
  float* sp2  = st2 + 20480;       // 4096
  float* G0   = st2 + 24576;       // 4096
  float* G1   = st2 + 28672;       // 4096
  float* bnp0 = st2 + 32768;       // 128
  float* bnp1 = bnp0 + 128;
  float* bnp2 = bnp1 + 128;
  u16*   W1b  = (u16*)(st2 + 33152);  // 4096 bf16 (scaled)
  u16*   W2b  = (u16*)(st2 + 35200);  // 4096 bf16 (scaled, unused in MFMA)
  u16*   W2r  = (u16*)(st2 + 37248);  // 4096 bf16 raw
  float* mraw = (float*)(ws + (9u << 20));       // 4 MiB: [b][n][64] raw maxima
  u16*   y0img = (u16*)(ws + (16u << 20));       // 64 MiB (FAT path only)
  bool fat = ws_size >= ((size_t)96 << 20);

  // zero Gp + rp0/rp1/sp1/sp2 + G0/G1 (contiguous: 2 MiB + 128 KiB)
  hipMemsetAsync(Gp, 0, (2u << 20) + 131072u, stream);

  k_copy<<<dim3(48), 256, 0, stream>>>((const uint4*)pos1, (uint4*)d_out);
  k_knn<<<dim3(1024, 4), 256, 0, stream>>>(pos1, pos2, idxb);
  k_precomp<0><<<dim3(64, 4), 256, 0, stream>>>(pos2, f2, W0, A);
  k_precomp<1><<<dim3(64, 4), 256, 0, stream>>>(pos1, f1, W0, Cn);
  k_cvtW2<<<dim3(1), 256, 0, stream>>>(W2, W2r);
  k_stats0<<<dim3(128, 4), 512, 0, stream>>>(idxb, A, Cn, sp1, sp2);
  k_bn0<<<dim3(1), 256, 0, stream>>>(sp1, sp2, g0, b0, bnp0);
  if (fat){
    k_gram0<1><<<dim3(128, 4), 512, 0, stream>>>(idxb, A, Cn, bnp0, Gp, rp0, y0img);
    k_reduceG<<<dim3(16, 8), 256, 0, stream>>>(Gp, G0);
    k_bnW<<<dim3(1), 256, 0, stream>>>(W1, rp0, G0, g1, b1, bnp1, W1b);
    k_gram1<1><<<dim3(128, 4), 512, 0, stream>>>(idxb, A, Cn, bnp0, W1b, W2r, bnp1,
                                                 Gp, rp1, y0img, mraw);
    k_reduceG<<<dim3(16, 8), 256, 0, stream>>>(Gp, G1);
    k_bnW<<<dim3(1), 256, 0, stream>>>(W2, rp1, G1, g2, b2, bnp2, W2b);
  } else {
    k_gram0<0><<<dim3(128, 4), 512, 0, stream>>>(idxb, A, Cn, bnp0, Gp, rp0, y0img);
    k_reduceG<<<dim3(16, 8), 256, 0, stream>>>(Gp, G0);
    k_bnW<<<dim3(1), 256, 0, stream>>>(W1, rp0, G0, g1, b1, bnp1, W1b);
    k_gram1<0><<<dim3(128, 4), 512, 0, stream>>>(idxb, A, Cn, bnp0, W1b, W2r, bnp1,
                                                 Gp, rp1, y0img, mraw);
    k_reduceG<<<dim3(16, 8), 256, 0, stream>>>(Gp, G1);
    k_bnW<<<dim3(1), 256, 0, stream>>>(W2, rp1, G1, g2, b2, bnp2, W2b);
  }
  k_epi<<<dim3(64, 4), 256, 0, stream>>>(mraw, bnp2, (float*)d_out);
}

// Round 20
// 254.600 us; speedup vs baseline: 1.0696x; 1.0696x over previous
//
#include <hip/hip_runtime.h>
#include <hip/hip_bf16.h>

// FlowEmbedding (B=4, N=M=4096, C=64, S=32, mlp=[64,64,64]) — f32 I/O.
// R20 = revert to R17 (best measured: 254.95us). R18 (barrier halving) was
//      neutral; R19 (512-thr dual-group, unconfounded) regressed — gram1 is
//      per-chunk dependency-chain-bound, not occupancy/barrier-bound.

#define N_ 4096
#define S_ 32
#define PTOT 524288.0f   // B*N*S

typedef unsigned short u16;
typedef unsigned int   u32;
typedef unsigned long long u64;
typedef __attribute__((ext_vector_type(8))) short short8;  // 8 bf16 (4 VGPR)
typedef __attribute__((ext_vector_type(4))) float f32x4;

__device__ __forceinline__ float b2f(u16 u){
  union { u32 i; float f; } x; x.i = ((u32)u) << 16; return x.f;
}
__device__ __forceinline__ u16 f2b(float f){
  __hip_bfloat16 h = __float2bfloat16(f);
  return *(u16*)&h;
}
// monotone float<->uint mapping for signed atomicMax
__device__ __forceinline__ u32 fenc(float f){
  u32 u = __float_as_uint(f);
  return (u & 0x80000000u) ? ~u : (u | 0x80000000u);
}
__device__ __forceinline__ float fdec(u32 k){
  return __uint_as_float((k & 0x80000000u) ? (k & 0x7FFFFFFFu) : ~k);
}
// swizzled u16 index into a [64][64] bf16 LDS tile (rows 128 B): conflict-free
__device__ __forceinline__ int TIX(int r, int c){ return (r << 6) + (c ^ ((r & 7) << 3)); }
#define MFMA16(a,b,c) __builtin_amdgcn_mfma_f32_16x16x32_bf16((a),(b),(c),0,0,0)

// ---------------- copy pos1 (output 0 passthrough) ---------------------------
__global__ void k_copy(const uint4* __restrict__ s, uint4* __restrict__ d){
  int i = blockIdx.x * 256 + threadIdx.x;   // 48 x 256 = 12288 exact
  d[i] = s[i];
}

// ---------------- KNN: per-lane counting + parallel rank-select --------------
#define PLCNT(T, OUT) { int _c = 0;                                           \
  _Pragma("unroll")                                                           \
  for (int _it = 0; _it < 64; ++_it) _c += (dl[_it] < (T)) ? 1 : 0;           \
  _Pragma("unroll")                                                           \
  for (int _d = 1; _d < 64; _d <<= 1) _c += __shfl_xor(_c, _d);               \
  OUT = (u32)_c; }

__global__ __launch_bounds__(256) void k_knn(const float* __restrict__ pos1,
        const float* __restrict__ pos2, int* __restrict__ idxb){
  __shared__ u64 lkey[4][96];
  int b = blockIdx.y;
  int l = threadIdx.x & 63;
  int w = threadIdx.x >> 6;
  int n = blockIdx.x * 4 + w;
  const float* p1 = pos1 + b * 3 * N_;
  const float* p2 = pos2 + b * 3 * N_;
  float qx = p1[n], qy = p1[N_ + n], qz = p1[2 * N_ + n];
  float dl[64];
  float minv = 3.4e38f;
  #pragma unroll
  for (int it = 0; it < 16; ++it){          // float4 loads: 4 points/iter
    int j0 = it * 256 + l * 4;
    float4 xv = *(const float4*)(p2 + j0);
    float4 yv = *(const float4*)(p2 + N_ + j0);
    float4 zv = *(const float4*)(p2 + 2 * N_ + j0);
    float dx, dy, dz, d;
    dx=xv.x-qx; dy=yv.x-qy; dz=zv.x-qz; d=fmaf(dx,dx,fmaf(dy,dy,dz*dz)); dl[it*4+0]=d; minv=fminf(minv,d);
    dx=xv.y-qx; dy=yv.y-qy; dz=zv.y-qz; d=fmaf(dx,dx,fmaf(dy,dy,dz*dz)); dl[it*4+1]=d; minv=fminf(minv,d);
    dx=xv.z-qx; dy=yv.z-qy; dz=zv.z-qz; d=fmaf(dx,dx,fmaf(dy,dy,dz*dz)); dl[it*4+2]=d; minv=fminf(minv,d);
    dx=xv.w-qx; dy=yv.w-qy; dz=zv.w-qz; d=fmaf(dx,dx,fmaf(dy,dy,dz*dz)); dl[it*4+3]=d; minv=fminf(minv,d);
  }
  #pragma unroll
  for (int d2 = 1; d2 < 64; d2 <<= 1) minv = fminf(minv, __shfl_xor(minv, d2));
  u32 lo = __float_as_uint(minv);
  u32 hi = lo + (5u << 23); if (hi > 0x7F800000u) hi = 0x7F800000u;
  u32 step = 2u << 23;
  u32 K = 0;
  for (int e = 0; e < 12; ++e){
    PLCNT(__uint_as_float(hi), K)
    if (K >= 32u) break;
    lo = hi;
    hi += step; if (hi > 0x7F800000u) hi = 0x7F800000u;
    step <<= 1;
  }
  if (K < 32u){ hi = 0x7F800000u; PLCNT(__uint_as_float(hi), K) }
  for (int itr = 0; itr < 28 && K > 96u && (hi - lo) > 1u; ++itr){
    u32 mid = (lo + hi) >> 1, c;
    PLCNT(__uint_as_float(mid), c)
    if (c >= 32u){ hi = mid; K = c; } else lo = mid;
  }
  float T = __uint_as_float(hi);
  lkey[w][l] = ~0ull;
  if (l < 32) lkey[w][64 + l] = ~0ull;
  int myc = 0;
  #pragma unroll
  for (int it = 0; it < 64; ++it) myc += (dl[it] < T) ? 1 : 0;
  int pre = myc;
  #pragma unroll
  for (int d2 = 1; d2 < 64; d2 <<= 1){
    int t2 = __shfl_up(pre, d2); if (l >= d2) pre += t2;
  }
  int slot = pre - myc;
  for (int it = 0; it < 64; ++it){
    if (dl[it] < T){
      if (slot < 96)
        lkey[w][slot] = ((u64)__float_as_uint(dl[it]) << 32)
                      | (u32)((it >> 2) * 256 + l * 4 + (it & 3));
      slot++;
    }
  }
  int Kc = (int)(K > 96u ? 96u : K);
  u64 k0 = lkey[w][l];
  u64 k1 = (l < 32) ? lkey[w][64 + l] : ~0ull;
  int r0 = 0, r1 = 0;
  for (int j = 0; j < 96; j += 2){
    ulonglong2 kp = *(const ulonglong2*)&lkey[w][j];
    r0 += (kp.x < k0) + (kp.y < k0);
    r1 += (kp.x < k1) + (kp.y < k1);
  }
  unsigned long long m0 = __ballot((l < Kc) && (r0 == 0));
  u32 nearest;
  if (m0) nearest = (u32)__shfl((int)(u32)k0, __builtin_ctzll(m0));
  else {
    unsigned long long m1 = __ballot((l + 64 < Kc) && (r1 == 0));
    nearest = (u32)__shfl((int)(u32)k1, __builtin_ctzll(m1));
  }
  int* op = idxb + (b * N_ + n) * S_;
  float d0 = __uint_as_float((u32)(k0 >> 32));
  float d1 = __uint_as_float((u32)(k1 >> 32));
  if ((l < Kc) && (r0 < 32))      op[r0] = (d0 > 25.0f) ? (int)nearest : (int)(u32)k0;
  if ((l + 64 < Kc) && (r1 < 32)) op[r1] = (d1 > 25.0f) ? (int)nearest : (int)(u32)k1;
}

// ---------------- layer-0 factorization -> bf16: A (MODE=0) / Cn (MODE=1) ---
template<int MODE>
__global__ __launch_bounds__(256) void k_precomp(const float* __restrict__ posx,
        const float* __restrict__ featx, const float* __restrict__ W0,
        u16* __restrict__ outp){
  __shared__ float Ws[67][65];
  __shared__ float Xs[67][65];
  int b = blockIdx.y, j0 = blockIdx.x * 64, t = threadIdx.x;
  for (int e = t; e < 67 * 64; e += 256){
    int r = e >> 6, o = e & 63;
    int wc = (MODE == 0) ? r : (r < 3 ? r : r + 64);
    Ws[r][o] = W0[o * 131 + wc];
    float x;
    if (r < 3){ x = posx[(b * 3 + r) * N_ + j0 + o]; if (MODE) x = -x; }
    else        x = featx[(b * 64 + (r - 3)) * N_ + j0 + o];
    Xs[r][o] = x;
  }
  __syncthreads();
  int og = t & 15, sl = t >> 4;
  float acc[4][4] = {};
  for (int r = 0; r < 67; ++r){
    float w0v = Ws[r][og*4+0], w1v = Ws[r][og*4+1], w2v = Ws[r][og*4+2], w3v = Ws[r][og*4+3];
    #pragma unroll
    for (int c = 0; c < 4; ++c){
      float xv = Xs[r][sl*4+c];
      acc[c][0] += xv*w0v; acc[c][1] += xv*w1v; acc[c][2] += xv*w2v; acc[c][3] += xv*w3v;
    }
  }
  #pragma unroll
  for (int c = 0; c < 4; ++c){
    ushort4 val;
    val.x = f2b(acc[c][0]); val.y = f2b(acc[c][1]);
    val.z = f2b(acc[c][2]); val.w = f2b(acc[c][3]);
    *(ushort4*)&outp[(((size_t)(b * N_ + j0 + sl*4 + c)) << 6) + og*4] = val;
  }
}

// ---------------- convert W2 f32 -> raw bf16 [o][c] --------------------------
__global__ void k_cvtW2(const float* __restrict__ W, u16* __restrict__ Wb){
  int t = threadIdx.x;
  for (int e = t; e < 4096; e += 256) Wb[e] = f2b(W[e]);
}

// ---------------- stats of h0 (pre-BN0): bf16 gather, slot partials ---------
__global__ __launch_bounds__(256) void k_stats0(const int* __restrict__ idxb,
    const u16* __restrict__ A, const u16* __restrict__ Cn,
    float* __restrict__ sp1, float* __restrict__ sp2){
  int b = blockIdx.y, n0 = blockIdx.x * 32;
  int c4 = threadIdx.x & 15, sq = threadIdx.x >> 4;
  float4 a1 = {0,0,0,0}, a2 = {0,0,0,0};
  for (int q = 0; q < 32; ++q){
    int n = n0 + q;
    ushort4 cu = *(const ushort4*)&Cn[(((size_t)(b * N_ + n)) << 6) + c4 * 4];
    float cx = b2f(cu.x), cy = b2f(cu.y), cz = b2f(cu.z), cw = b2f(cu.w);
    const int* ip = idxb + (b * N_ + n) * 32;
    #pragma unroll
    for (int ss = 0; ss < 2; ++ss){
      int j = ip[sq + ss * 16];
      ushort4 au = *(const ushort4*)&A[(((size_t)(b * N_ + j)) << 6) + c4 * 4];
      float h0 = b2f(au.x) + cx, h1 = b2f(au.y) + cy;
      float h2 = b2f(au.z) + cz, h3 = b2f(au.w) + cw;
      a1.x += h0; a1.y += h1; a1.z += h2; a1.w += h3;
      a2.x += h0*h0; a2.y += h1*h1; a2.z += h2*h2; a2.w += h3*h3;
    }
  }
  __shared__ float red1[16][64];
  __shared__ float red2[16][64];
  *(float4*)&red1[sq][c4*4] = a1;
  *(float4*)&red2[sq][c4*4] = a2;
  __syncthreads();
  int t = threadIdx.x;
  int slot = (blockIdx.x + (blockIdx.y << 7)) & 63;
  if (t < 64){
    float s1 = 0.f, s2 = 0.f;
    #pragma unroll
    for (int k = 0; k < 16; ++k){ s1 += red1[k][t]; s2 += red2[k][t]; }
    atomicAdd(&sp1[slot * 64 + t], s1);
    atomicAdd(&sp2[slot * 64 + t], s2);
  }
}

// ---------------- BN param kernels (parallelized) ----------------------------
__global__ __launch_bounds__(256) void k_bn0(const float* __restrict__ sp1,
    const float* __restrict__ sp2, const float* g, const float* bb, float* bnp){
  __shared__ float red1[4][64];
  __shared__ float red2[4][64];
  int t = threadIdx.x, c = t & 63, s = t >> 6;
  float s1 = 0.f, s2 = 0.f;
  for (int k = s * 16; k < s * 16 + 16; ++k){
    s1 += sp1[k * 64 + c]; s2 += sp2[k * 64 + c];
  }
  red1[s][c] = s1; red2[s][c] = s2;
  __syncthreads();
  if (t < 64){
    float a1 = red1[0][c] + red1[1][c] + red1[2][c] + red1[3][c];
    float a2 = red2[0][c] + red2[1][c] + red2[2][c] + red2[3][c];
    float m = a1 * (1.0f / PTOT);
    float v = a2 * (1.0f / PTOT) - m * m;
    v = v > 0.f ? v : 0.f;
    float sc = g[c] * rsqrtf(v + 1e-5f);
    bnp[c] = sc; bnp[64 + c] = bb[c] - m * sc;
  }
}

__global__ __launch_bounds__(256) void k_bnW(const float* __restrict__ W,
    const float* __restrict__ rp, const float* __restrict__ G, const float* g,
    const float* bb, float* bnp, u16* __restrict__ Wb){
  __shared__ float Ws[64][65];
  __shared__ float Gs[64][65];
  __shared__ float r_s[64];
  __shared__ float redA[4][64];
  __shared__ float redB[4][64];
  __shared__ float scs[64];
  int t = threadIdx.x, o = t & 63, s = t >> 6;
  for (int e = t; e < 4096; e += 256){
    Ws[e >> 6][e & 63] = W[e];
    Gs[e >> 6][e & 63] = G[e];
  }
  float rv = 0.f;
  for (int k = s * 32; k < s * 32 + 32; ++k) rv += rp[k * 64 + o];
  redA[s][o] = rv;
  __syncthreads();
  if (s == 0) r_s[o] = redA[0][o] + redA[1][o] + redA[2][o] + redA[3][o];
  __syncthreads();
  float pm = 0.f, pq = 0.f;
  for (int c = s * 16; c < s * 16 + 16; ++c){
    float t1 = 0.f;
    #pragma unroll
    for (int d = 0; d < 64; ++d) t1 = fmaf(Gs[c][d], Ws[o][d], t1);
    pm = fmaf(Ws[o][c], r_s[c], pm);
    pq = fmaf(Ws[o][c], t1, pq);
  }
  __syncthreads();
  redA[s][o] = pm; redB[s][o] = pq;
  __syncthreads();
  if (t < 64){
    float mean = redA[0][o] + redA[1][o] + redA[2][o] + redA[3][o];
    float qq   = redB[0][o] + redB[1][o] + redB[2][o] + redB[3][o];
    float m = mean * (1.0f / PTOT);
    float v = qq * (1.0f / PTOT) - m * m;
    v = v > 0.f ? v : 0.f;
    float sc = g[o] * rsqrtf(v + 1e-5f);
    bnp[o] = sc; bnp[64 + o] = bb[o] - m * sc;
    scs[o] = sc;
  }
  __syncthreads();
  for (int e = t; e < 4096; e += 256){
    int oo = e >> 6, cc = e & 63;
    Wb[e] = f2b(scs[oo] * Ws[oo][cc]);
  }
}

// ------ reduce 128 partial grams -> G (parallel slot-split, 16x8 grid) ------
__global__ void k_reduceG(float* __restrict__ Gp, float* __restrict__ Gout){
  int e = blockIdx.x * 256 + threadIdx.x;
  int s0 = blockIdx.y * 16;
  float v = 0.f;
  for (int s = s0; s < s0 + 16; ++s) v += Gp[s * 4096 + e];
  atomicAdd(&Gout[e], v);                    // Gout pre-zeroed by memset
  for (int s = s0; s < s0 + 16; ++s) Gp[s * 4096 + e] = 0.f;
}

// gather one 64-point chunk from bf16 A/Cn: y0 = relu(fma(sc0, A+Cn, sh0))
#define GATHER_Y0(YARR)                                                       \
  int nq = n0 + ch * 2 + (l >> 5);                                            \
  int jj = idxb[((b << 12) + nq) * 32 + (l & 31)];                            \
  const u16* ap = A + (((size_t)((b << 12) + jj)) << 6) + (w << 4);           \
  const u16* cp = Cn + (((size_t)((b << 12) + nq)) << 6) + (w << 4);          \
  short8 ga0 = *(const short8*)(ap);                                          \
  short8 ga1 = *(const short8*)(ap + 8);                                      \
  short8 gc0 = *(const short8*)(cp);                                          \
  short8 gc1 = *(const short8*)(cp + 8);                                      \
  float YARR[16];                                                             \
  _Pragma("unroll")                                                           \
  for (int kk = 0; kk < 16; ++kk){                                            \
    u16 ae = (kk < 8) ? (u16)ga0[kk] : (u16)ga1[kk - 8];                      \
    u16 ce = (kk < 8) ? (u16)gc0[kk] : (u16)gc1[kk - 8];                      \
    float hv = b2f(ae) + b2f(ce);                                             \
    float sc = ((const float*)scv)[kk], sh = ((const float*)shv)[kk];         \
    YARR[kk] = fmaxf(fmaf(sc, hv, sh), 0.f);                                  \
  }

#define LOAD_BN0                                                              \
  float4 scv[4], shv[4];                                                      \
  _Pragma("unroll")                                                           \
  for (int k = 0; k < 4; ++k){                                                \
    scv[k] = *((const float4*)bnp0 + (w << 2) + k);                           \
    shv[k] = *((const float4*)bnp0 + 16 + (w << 2) + k);                      \
  }

// issue gathers for chunk CH into pga/pgc regs (per-lane)
#define ISSUE_GATHER(CH)                                                      \
  {                                                                           \
    int nq = n0 + (CH) * 2 + (l >> 5);                                        \
    const u16* ap = A + (((size_t)((b << 12) + idxpre[CH])) << 6) + (w << 4); \
    const u16* cp = Cn + (((size_t)((b << 12) + nq)) << 6) + (w << 4);        \
    pga0 = *(const short8*)(ap);  pga1 = *(const short8*)(ap + 8);            \
    pgc0 = *(const short8*)(cp);  pgc1 = *(const short8*)(cp + 8);            \
  }

// convert prefetched regs to y0 values
#define CONSUME_Y0(YARR)                                                      \
  float YARR[16];                                                             \
  _Pragma("unroll")                                                           \
  for (int kk = 0; kk < 16; ++kk){                                            \
    u16 ae = (kk < 8) ? (u16)pga0[kk] : (u16)pga1[kk - 8];                    \
    u16 ce = (kk < 8) ? (u16)pgc0[kk] : (u16)pgc1[kk - 8];                    \
    float hv = b2f(ae) + b2f(ce);                                             \
    float sc = ((const float*)scv)[kk], sh = ((const float*)shv)[kk];         \
    YARR[kk] = fmaxf(fmaf(sc, hv, sh), 0.f);                                  \
  }

// ---------------- gram0: pipelined gather; FAT: export y0 images ------------
template<int FAT>
__global__ __launch_bounds__(256) void k_gram0(const int* __restrict__ idxb,
    const u16* __restrict__ A, const u16* __restrict__ Cn,
    const float* __restrict__ bnp0, float* __restrict__ Gp, float* __restrict__ rp0,
    u16* __restrict__ y0img){
  __shared__ u16 yc[4096];                   // y0 [c][p] bf16, swizzled
  __shared__ u16 yp[FAT ? 4096 : 64];        // y0 [p][c], only for export
  int b = blockIdx.y, n0 = blockIdx.x * 32, t = threadIdx.x;
  int l = t & 63, w = t >> 6;
  LOAD_BN0
  // preload all per-lane neighbor indices (16 chunks)
  int idxpre[16];
  #pragma unroll
  for (int ch = 0; ch < 16; ++ch){
    int nq = n0 + ch * 2 + (l >> 5);
    idxpre[ch] = idxb[((b << 12) + nq) * 32 + (l & 31)];
  }
  short8 pga0, pga1, pgc0, pgc1;
  ISSUE_GATHER(0)
  f32x4 acc[4] = {};
  float rsum[16] = {};
  for (int ch = 0; ch < 16; ++ch){
    CONSUME_Y0(yv)
    #pragma unroll
    for (int k = 0; k < 16; ++k){
      rsum[k] += yv[k];
      yc[TIX((w << 4) + k, l)] = f2b(yv[k]);
    }
    if (FAT){
      short8 s0v, s1v;
      #pragma unroll
      for (int i = 0; i < 8; ++i){ s0v[i] = (short)f2b(yv[i]); s1v[i] = (short)f2b(yv[8+i]); }
      *(short8*)&yp[TIX(l, (w<<4))] = s0v;
      *(short8*)&yp[TIX(l, (w<<4) + 8)] = s1v;
    }
    if (ch + 1 < 16) ISSUE_GATHER(ch + 1)
    __syncthreads();
    #pragma unroll
    for (int ks = 0; ks < 2; ++ks){
      short8 bf = *(const short8*)&yc[TIX((w << 4) + (l & 15), ks * 32 + ((l >> 4) << 3))];
      #pragma unroll
      for (int ta = 0; ta < 4; ++ta){
        short8 af = *(const short8*)&yc[TIX(ta * 16 + (l & 15), ks * 32 + ((l >> 4) << 3))];
        acc[ta] = MFMA16(af, bf, acc[ta]);
      }
    }
    if (FAT){                                // export yp tile, coalesced 32B/thr
      int rr = t >> 2, c0i = (t & 3) << 4;
      short8 e0 = *(const short8*)&yp[TIX(rr, c0i)];
      short8 e1 = *(const short8*)&yp[TIX(rr, c0i + 8)];
      size_t gb = ((((size_t)(((blockIdx.y << 7) | blockIdx.x) << 4) + ch) << 12)
                   + (rr << 6) + c0i);
      *(short8*)&y0img[gb] = e0;
      *(short8*)&y0img[gb + 8] = e1;
    }
    __syncthreads();
  }
  int slot = ((blockIdx.x << 2) + blockIdx.y) & 127;
  float* gp = Gp + slot * 4096;
  #pragma unroll
  for (int ta = 0; ta < 4; ++ta)
    #pragma unroll
    for (int r = 0; r < 4; ++r)
      atomicAdd(&gp[(ta*16 + ((l>>4)<<2) + r) * 64 + (w<<4) + (l & 15)], acc[ta][r]);
  #pragma unroll
  for (int i = 0; i < 16; ++i){
    float v = rsum[i];
    #pragma unroll
    for (int s = 32; s >= 1; s >>= 1) v += __shfl_xor(v, s);
    if (l == 0) atomicAdd(&rp0[slot * 64 + (w<<4) + i], v);
  }
}

// -------- gram1: y1=relu(W1b*y0+sh1); G1 partials; h2 maxpool; prefetch -----
template<int FAT>
__global__ __launch_bounds__(256) void k_gram1(const int* __restrict__ idxb,
    const u16* __restrict__ A, const u16* __restrict__ Cn,
    const float* __restrict__ bnp0, const u16* __restrict__ W1b,
    const u16* __restrict__ W2r, const float* __restrict__ bnp1,
    float* __restrict__ Gp, float* __restrict__ rp1,
    const u16* __restrict__ y0img, float* __restrict__ mraw){
  __shared__ u16 yp[2][4096];                // y0 [p][c], double-buffered
  __shared__ u16 y1c[4096];                  // y1 [c][p]
  __shared__ u16 y1p[4096];                  // y1 [p][c]
  __shared__ u32 omax[2048];                 // [qloc 0..31][o] fenc-coded
  __shared__ float sh1[64];
  __shared__ float rsh[64];
  int b = blockIdx.y, n0 = blockIdx.x * 32, t = threadIdx.x;
  int l = t & 63, w = t >> 6;
  LOAD_BN0
  if (t < 64){ sh1[t] = bnp1[64 + t]; rsh[t] = 0.f; }
  for (int e = t; e < 2048; e += 256) omax[e] = 0u;
  short8 wf[4][2], wf2[4][2];
  #pragma unroll
  for (int to = 0; to < 4; ++to)
    #pragma unroll
    for (int ks = 0; ks < 2; ++ks){
      wf[to][ks]  = *(const short8*)&W1b[(to*16 + (l & 15)) * 64 + ks*32 + ((l>>4)<<3)];
      wf2[to][ks] = *(const short8*)&W2r[(to*16 + (l & 15)) * 64 + ks*32 + ((l>>4)<<3)];
    }
  float sh1v[4][4];
  // prologue: load chunk 0 into yp[0]
  int rr = t >> 2, c0i = (t & 3) << 4;
  size_t gbase = ((((size_t)(((blockIdx.y << 7) | blockIdx.x) << 4)) << 12)
                  + (rr << 6) + c0i);
  int cur = 0;
  short8 pe0, pe1;
  if (FAT){
    pe0 = *(const short8*)&y0img[gbase];
    pe1 = *(const short8*)&y0img[gbase + 8];
    *(short8*)&yp[0][TIX(rr, c0i)] = pe0;
    *(short8*)&yp[0][TIX(rr, c0i + 8)] = pe1;
  }
  __syncthreads();
  #pragma unroll
  for (int to = 0; to < 4; ++to)
    #pragma unroll
    for (int r = 0; r < 4; ++r)
      sh1v[to][r] = sh1[to*16 + ((l>>4)<<2) + r];
  f32x4 gacc[4] = {};
  float rs[4][4] = {};
  for (int ch = 0; ch < 16; ++ch){
    if (FAT){
      if (ch + 1 < 16){                      // prefetch next chunk into regs
        size_t gb = gbase + ((size_t)(ch + 1) << 12);
        pe0 = *(const short8*)&y0img[gb];
        pe1 = *(const short8*)&y0img[gb + 8];
      }
    } else {
      GATHER_Y0(yv)
      short8 s0, s1;
      #pragma unroll
      for (int i = 0; i < 8; ++i){ s0[i] = (short)f2b(yv[i]); s1[i] = (short)f2b(yv[8+i]); }
      *(short8*)&yp[0][TIX(l, (w<<4))] = s0;
      *(short8*)&yp[0][TIX(l, (w<<4) + 8)] = s1;
      __syncthreads();
    }
    // layer1: D[o][p] = sum_c W1b[o][c] * y0[c][p]
    short8 bf0 = *(const short8*)&yp[cur][TIX((w<<4) + (l & 15), ((l>>4)<<3))];
    short8 bf1 = *(const short8*)&yp[cur][TIX((w<<4) + (l & 15), 32 + ((l>>4)<<3))];
    f32x4 h[4] = {};
    #pragma unroll
    for (int to = 0; to < 4; ++to){
      h[to] = MFMA16(wf[to][0], bf0, h[to]);
      h[to] = MFMA16(wf[to][1], bf1, h[to]);
    }
    int pcol = (w<<4) + (l & 15);
    #pragma unroll
    for (int to = 0; to < 4; ++to){
      ushort4 sv;
      #pragma unroll
      for (int r = 0; r < 4; ++r){
        int o = to*16 + ((l>>4)<<2) + r;
        float y = h[to][r] + sh1v[to][r];
        y = y > 0.f ? y : 0.f;
        rs[to][r] += y;
        u16 yb = f2b(y);
        y1c[TIX(o, pcol)] = yb;
        ((u16*)&sv)[r] = yb;
      }
      *(ushort4*)&y1p[TIX(pcol, to*16 + ((l>>4)<<2))] = sv;
    }
    __syncthreads();
    // gram over y1
    #pragma unroll
    for (int ks = 0; ks < 2; ++ks){
      short8 bf = *(const short8*)&y1c[TIX((w<<4) + (l & 15), ks*32 + ((l>>4)<<3))];
      #pragma unroll
      for (int ta = 0; ta < 4; ++ta){
        short8 af = *(const short8*)&y1c[TIX(ta*16 + (l & 15), ks*32 + ((l>>4)<<3))];
        gacc[ta] = MFMA16(af, bf, gacc[ta]);
      }
    }
    // layer2 raw + maxpool (bn2 applied in k_epi; s2>0 since g2=1)
    short8 c0 = *(const short8*)&y1p[TIX(pcol, ((l>>4)<<3))];
    short8 c1 = *(const short8*)&y1p[TIX(pcol, 32 + ((l>>4)<<3))];
    f32x4 h2[4] = {};
    #pragma unroll
    for (int to = 0; to < 4; ++to){
      h2[to] = MFMA16(wf2[to][0], c0, h2[to]);
      h2[to] = MFMA16(wf2[to][1], c1, h2[to]);
    }
    int qloc = ch * 2 + (w >> 1);
    #pragma unroll
    for (int to = 0; to < 4; ++to)
      #pragma unroll
      for (int r = 0; r < 4; ++r){
        float m = h2[to][r];
        #pragma unroll
        for (int s = 1; s <= 8; s <<= 1) m = fmaxf(m, __shfl_xor(m, s));
        if ((l & 15) == 0)
          atomicMax(&omax[qloc*64 + to*16 + ((l>>4)<<2) + r], fenc(m));
      }
    if (FAT && ch + 1 < 16){                 // commit prefetch to other buffer
      *(short8*)&yp[cur ^ 1][TIX(rr, c0i)] = pe0;
      *(short8*)&yp[cur ^ 1][TIX(rr, c0i + 8)] = pe1;
    }
    __syncthreads();
    if (FAT) cur ^= 1;
  }
  int slot = ((blockIdx.x << 2) + blockIdx.y) & 127;
  float* gp = Gp + slot * 4096;
  #pragma unroll
  for (int ta = 0; ta < 4; ++ta)
    #pragma unroll
    for (int r = 0; r < 4; ++r)
      atomicAdd(&gp[(ta*16 + ((l>>4)<<2) + r) * 64 + (w<<4) + (l & 15)], gacc[ta][r]);
  #pragma unroll
  for (int to = 0; to < 4; ++to)
    #pragma unroll
    for (int r = 0; r < 4; ++r){
      float v = rs[to][r];
      #pragma unroll
      for (int s = 1; s <= 8; s <<= 1) v += __shfl_xor(v, s);
      if ((l & 15) == 0) atomicAdd(&rsh[to*16 + ((l>>4)<<2) + r], v);
    }
  __syncthreads();
  if (t < 64) atomicAdd(&rp1[slot * 64 + t], rsh[t]);
  for (int e = t; e < 2048; e += 256){
    int q = e >> 6, o = e & 63;
    mraw[(((size_t)((b << 12) + n0 + q)) << 6) + o] = fdec(omax[e]);
  }
}

// ---------------- epilogue: out = relu(s2*mraw + t2), transpose -------------
__global__ __launch_bounds__(256) void k_epi(const float* __restrict__ mraw,
    const float* __restrict__ bnp2, float* __restrict__ outp){
  __shared__ float tile[64][65];
  int b = blockIdx.y, n0 = blockIdx.x * 64, t = threadIdx.x;
  int o = t & 63, w = t >> 6;
  float sc = bnp2[o], sh = bnp2[64 + o];
  #pragma unroll
  for (int i = 0; i < 16; ++i){
    int n = i * 4 + w;
    float m = mraw[(((size_t)((b << 12) + n0 + n)) << 6) + o];
    float y = fmaf(sc, m, sh);
    tile[n][o] = y > 0.f ? y : 0.f;
  }
  __syncthreads();
  #pragma unroll
  for (int i = 0; i < 16; ++i){
    int oo = i * 4 + w;
    outp[49152 + ((size_t)((b << 6) + oo)) * N_ + n0 + o] = tile[o][oo];
  }
}

extern "C" void kernel_launch(void* const* d_in, const int* in_sizes, int n_in,
                              void* d_out, int out_size, void* d_ws, size_t ws_size,
                              hipStream_t stream){
  (void)in_sizes; (void)n_in; (void)out_size;
  const float* pos1 = (const float*)d_in[0];
  const float* pos2 = (const float*)d_in[1];
  const float* f1   = (const float*)d_in[2];
  const float* f2   = (const float*)d_in[3];
  const float* W0   = (const float*)d_in[4];
  const float* g0   = (const float*)d_in[5];
  const float* b0   = (const float*)d_in[6];
  const float* W1   = (const float*)d_in[7];
  const float* g1   = (const float*)d_in[8];
  const float* b1   = (const float*)d_in[9];
  const float* W2   = (const float*)d_in[10];
  const float* g2   = (const float*)d_in[11];
  const float* b2   = (const float*)d_in[12];

  char* ws = (char*)d_ws;
  int*   idxb = (int*)ws;                        // 2 MiB: idx[B][N][32]
  u16*   A    = (u16*)(ws + (2u << 20));         // 2 MiB: A[b][j][64] bf16
  u16*   Cn   = (u16*)(ws + (4u << 20));         // 2 MiB: Cn[b][n][64] bf16
  float* Gp   = (float*)(ws + (6u << 20));       // 2 MiB: 128 x 4096 partials
  float* st2  = (float*)(ws + (8u << 20));
  float* rp0  = st2;               // 128*64 = 8192
  float* rp1  = st2 + 8192;        // 8192
  float* sp1  = st2 + 16384;       // 64*64 = 4096
  float* sp2  = st2 + 20480;       // 4096
  float* G0   = st2 + 24576;       // 4096
  float* G1   = st2 + 28672;       // 4096
  float* bnp0 = st2 + 32768;       // 128
  float* bnp1 = bnp0 + 128;
  float* bnp2 = bnp1 + 128;
  u16*   W1b  = (u16*)(st2 + 33152);  // 4096 bf16 (scaled)
  u16*   W2b  = (u16*)(st2 + 35200);  // 4096 bf16 (scaled, unused in MFMA)
  u16*   W2r  = (u16*)(st2 + 37248);  // 4096 bf16 raw
  float* mraw = (float*)(ws + (9u << 20));       // 4 MiB: [b][n][64] raw maxima
  u16*   y0img = (u16*)(ws + (16u << 20));       // 64 MiB (FAT path only)
  bool fat = ws_size >= ((size_t)96 << 20);

  // zero Gp + rp0/rp1/sp1/sp2 + G0/G1 (contiguous: 2 MiB + 128 KiB)
  hipMemsetAsync(Gp, 0, (2u << 20) + 131072u, stream);

  k_copy<<<dim3(48), 256, 0, stream>>>((const uint4*)pos1, (uint4*)d_out);
  k_knn<<<dim3(1024, 4), 256, 0, stream>>>(pos1, pos2, idxb);
  k_precomp<0><<<dim3(64, 4), 256, 0, stream>>>(pos2, f2, W0, A);
  k_precomp<1><<<dim3(64, 4), 256, 0, stream>>>(pos1, f1, W0, Cn);
  k_cvtW2<<<dim3(1), 256, 0, stream>>>(W2, W2r);
  k_stats0<<<dim3(128, 4), 256, 0, stream>>>(idxb, A, Cn, sp1, sp2);
  k_bn0<<<dim3(1), 256, 0, stream>>>(sp1, sp2, g0, b0, bnp0);
  if (fat){
    k_gram0<1><<<dim3(128, 4), 256, 0, stream>>>(idxb, A, Cn, bnp0, Gp, rp0, y0img);
    k_reduceG<<<dim3(16, 8), 256, 0, stream>>>(Gp, G0);
    k_bnW<<<dim3(1), 256, 0, stream>>>(W1, rp0, G0, g1, b1, bnp1, W1b);
    k_gram1<1><<<dim3(128, 4), 256, 0, stream>>>(idxb, A, Cn, bnp0, W1b, W2r, bnp1,
                                                 Gp, rp1, y0img, mraw);
    k_reduceG<<<dim3(16, 8), 256, 0, stream>>>(Gp, G1);
    k_bnW<<<dim3(1), 256, 0, stream>>>(W2, rp1, G1, g2, b2, bnp2, W2b);
  } else {
    k_gram0<0><<<dim3(128, 4), 256, 0, stream>>>(idxb, A, Cn, bnp0, Gp, rp0, y0img);
    k_reduceG<<<dim3(16, 8), 256, 0, stream>>>(Gp, G0);
    k_bnW<<<dim3(1), 256, 0, stream>>>(W1, rp0, G0, g1, b1, bnp1, W1b);
    k_gram1<0><<<dim3(128, 4), 256, 0, stream>>>(idxb, A, Cn, bnp0, W1b, W2r, bnp1,
                                                 Gp, rp1, y0img, mraw);
    k_reduceG<<<dim3(16, 8), 256, 0, stream>>>(Gp, G1);
    k_bnW<<<dim3(1), 256, 0, stream>>>(W2, rp1, G1, g2, b2, bnp2, W2b);
  }
  k_epi<<<dim3(64, 4), 256, 0, stream>>>(mraw, bnp2, (float*)d_out);
}